// Round 3
// baseline (1430.909 us; speedup 1.0000x reference)
//
#include <hip/hip_runtime.h>
#include <stdint.h>

typedef unsigned short u16;
typedef __attribute__((ext_vector_type(8))) short short8;
typedef __attribute__((ext_vector_type(4))) float f32x4;

// ---------- bf16 helpers ----------
__device__ __forceinline__ float b2f(u16 x){
  union { unsigned u; float f; } v; v.u = ((unsigned)x) << 16; return v.f;
}
__device__ __forceinline__ float b2fs(short x){ return b2f((u16)x); }
__device__ __forceinline__ u16 f2b(float f){
  union { float f; unsigned u; } v; v.f = f;
  unsigned u = v.u;
  u += 0x7FFFu + ((u >> 16) & 1u);   // round-to-nearest-even
  return (u16)(u >> 16);
}
// dtype-flexible scalar load from a RAW harness input buffer
__device__ __forceinline__ float ldg_f(const void* p, int i, int f32){
  return f32 ? ((const float*)p)[i] : b2f(((const u16*)p)[i]);
}

// ---------- kernel 0: detect raw input dtype (bf16 vs fp32) ----------
// Even-indexed u16s of fp32 data are low mantissa halves (~uniform bits ->
// ~16% plausible bf16 exponents); of bf16 N(0,1) data they are real values
// (~100% plausible). flag=1 -> fp32, flag=0 -> bf16.
__global__ void detect_dtype(const u16* __restrict__ hid, int* __restrict__ flag){
  if (blockIdx.x == 0 && threadIdx.x == 0){
    int plaus = 0;
    for (int i = 0; i < 512; i++){
      u16 v = hid[2 * i];
      int e = (v >> 7) & 0xFF;
      if ((e >= 100 && e <= 140) || (v & 0x7FFF) == 0) plaus++;
    }
    *flag = (plaus < 400) ? 1 : 0;
  }
}

// ---------- kernel 1: t = bf16(hidden + pose) ----------
__global__ void make_t(const void* __restrict__ hid, const void* __restrict__ pose,
                       u16* __restrict__ t, const int* __restrict__ flag){
  int i = blockIdx.x * 256 + threadIdx.x;
  int f = *flag;
  t[i] = f2b(ldg_f(hid, i, f) + ldg_f(pose, i, f));
}

// ---------- kernel 2: WT[rowOff+n][k] = w[k][n] (+ rank-4 LoRA fold) ----------
__global__ void prep_w(const void* __restrict__ w, const void* __restrict__ dn,
                       const void* __restrict__ up, u16* __restrict__ WT,
                       int rowOff, const int* __restrict__ flag)
{
  int idx = blockIdx.x * 256 + threadIdx.x;   // 1280*1280 threads
  int k = idx % 1280, n = idx / 1280;
  int f = *flag;
  float val = ldg_f(w, k * 1280 + n, f);
  if (dn){
    #pragma unroll
    for (int r = 0; r < 4; r++)
      val += ldg_f(dn, k * 4 + r, f) * ldg_f(up, r * 1280 + n, f);
  }
  WT[(rowOff + n) * 1280 + k] = f2b(val);
}

// ---------- kernel 3: bf16 MFMA GEMM: C = A @ BT^T (+bias)(+resid) ----------
// A [M][K] bf16 (always our ws), BT [N][K] bf16 (ws). bias/resid are RAW
// harness buffers (dtype per flag). RAWOUT: store per flag (d_out).
template<bool BIAS, bool RESID, bool RAWOUT>
__global__ __launch_bounds__(256) void gemm_bt(
    const u16* __restrict__ A, const u16* __restrict__ BT,
    const void* __restrict__ bias, const void* __restrict__ resid,
    void* __restrict__ Cout, int Mdim, int Ndim, int Kdim,
    const int* __restrict__ flag)
{
  __shared__ alignas(16) u16 As[128 * 32];
  __shared__ alignas(16) u16 Bs[128 * 32];
  const int tid  = threadIdx.x;
  const int lane = tid & 63;
  const int w    = tid >> 6;
  const int wm   = w >> 1, wn = w & 1;
  const int quad = lane >> 4, l15 = lane & 15;
  const int tileM = blockIdx.y << 7;
  const int tileN = blockIdx.x << 7;
  const int f32 = (BIAS || RESID || RAWOUT) ? *flag : 0;

  f32x4 acc[4][4];
  #pragma unroll
  for (int mi = 0; mi < 4; mi++)
    #pragma unroll
    for (int ni = 0; ni < 4; ni++)
      acc[mi][ni] = (f32x4){0.f, 0.f, 0.f, 0.f};

  for (int k0 = 0; k0 < Kdim; k0 += 32){
    #pragma unroll
    for (int cc = 0; cc < 2; cc++){
      int c   = tid + (cc << 8);          // 0..511
      int row = c >> 2;
      int ko  = (c & 3) << 3;
      *(short8*)&As[c * 8] = *(const short8*)&A [(tileM + row) * Kdim + k0 + ko];
      *(short8*)&Bs[c * 8] = *(const short8*)&BT[(tileN + row) * Kdim + k0 + ko];
    }
    __syncthreads();

    short8 af[4], bfr[4];
    #pragma unroll
    for (int mi = 0; mi < 4; mi++)
      af[mi] = *(const short8*)(As + (wm * 64 + mi * 16 + l15) * 32 + quad * 8);
    #pragma unroll
    for (int ni = 0; ni < 4; ni++)
      bfr[ni] = *(const short8*)(Bs + (wn * 64 + ni * 16 + l15) * 32 + quad * 8);
    #pragma unroll
    for (int mi = 0; mi < 4; mi++)
      #pragma unroll
      for (int ni = 0; ni < 4; ni++)
        acc[mi][ni] = __builtin_amdgcn_mfma_f32_16x16x32_bf16(
            af[mi], bfr[ni], acc[mi][ni], 0, 0, 0);
    __syncthreads();
  }

  // epilogue: C/D layout col=lane&15, row=quad*4+reg  [m89/m91 verified]
  #pragma unroll
  for (int mi = 0; mi < 4; mi++){
    #pragma unroll
    for (int ni = 0; ni < 4; ni++){
      int col = tileN + wn * 64 + ni * 16 + l15;
      float bv = 0.f;
      if (BIAS) bv = ldg_f(bias, col, f32);
      #pragma unroll
      for (int r = 0; r < 4; r++){
        int row = tileM + wm * 64 + mi * 16 + quad * 4 + r;
        float v = acc[mi][ni][r] + bv;
        if (RESID) v += ldg_f(resid, row * Ndim + col, f32);
        if (RAWOUT && f32) ((float*)Cout)[row * Ndim + col] = v;
        else               ((u16*)Cout)[row * Ndim + col]   = f2b(v);
      }
    }
  }
}

// ---------- kernel 4: flash attention (online softmax), VALU f32 ----------
// qkv [8192][3840] bf16 (q|k|v each [*,1280], head h at col h*160+d)
// out [8192][1280] bf16. Grid (S/32, B*H). TQ=TK=32, 256 threads.
__global__ __launch_bounds__(256) void attn_flash(
    const u16* __restrict__ qkv, u16* __restrict__ out)
{
  __shared__ alignas(16) u16 qs[32][168];
  __shared__ alignas(16) u16 ks[32][168];
  __shared__ alignas(16) float vs[32][164];
  __shared__ float ss[32][33];
  __shared__ float mrow[32], lrow[32], arow[32];

  const int tid = threadIdx.x;
  const int bh  = blockIdx.y;
  const int b   = bh >> 3, h = bh & 7;
  const int q0  = blockIdx.x << 5;
  const int rowBase  = (b << 10) + q0;
  const int kRowBase = (b << 10);
  const int ty = tid >> 4, tx = tid & 15;
  const int qa = 2 * ty, qb = 2 * ty + 1;
  const float scale = 0.07905694150420949f;  // 160^-0.5

  #pragma unroll
  for (int i = 0; i < 5; i++){
    int e = tid + (i << 8);
    int r = e / 40, c = e % 40;
    *(ushort4*)&qs[r][4 * c] =
        *(const ushort4*)&qkv[(rowBase + r) * 3840 + h * 160 + 4 * c];
  }
  if (tid < 32){ mrow[tid] = -1e30f; lrow[tid] = 0.0f; arow[tid] = 0.0f; }

  float o0[5][2], o1[5][2];
  #pragma unroll
  for (int jj = 0; jj < 5; jj++){
    o0[jj][0] = o0[jj][1] = o1[jj][0] = o1[jj][1] = 0.f;
  }

  for (int kt = 0; kt < 32; kt++){
    __syncthreads();
    #pragma unroll
    for (int i = 0; i < 5; i++){
      int e = tid + (i << 8);
      int r = e / 40, c = e % 40;
      *(ushort4*)&ks[r][4 * c] =
          *(const ushort4*)&qkv[(kRowBase + kt * 32 + r) * 3840 + 1280 + h * 160 + 4 * c];
    }
    #pragma unroll
    for (int i = 0; i < 10; i++){
      int e = tid + (i << 8);
      int r = e / 80, c = e % 80;
      ushort2 vv = *(const ushort2*)&qkv[(kRowBase + kt * 32 + r) * 3840 + 2560 + h * 160 + 2 * c];
      vs[r][2 * c]     = b2f(vv.x);
      vs[r][2 * c + 1] = b2f(vv.y);
    }
    __syncthreads();

    float s00 = 0.f, s01 = 0.f, s10 = 0.f, s11 = 0.f;
    #pragma unroll 4
    for (int d = 0; d < 160; d += 8){
      short8 qav = *(const short8*)&qs[qa][d];
      short8 qbv = *(const short8*)&qs[qb][d];
      short8 kav = *(const short8*)&ks[tx][d];
      short8 kbv = *(const short8*)&ks[tx + 16][d];
      #pragma unroll
      for (int i = 0; i < 8; i++){
        float fa = b2fs(qav[i]), fb = b2fs(qbv[i]);
        float ga = b2fs(kav[i]), gb = b2fs(kbv[i]);
        s00 += fa * ga; s01 += fa * gb;
        s10 += fb * ga; s11 += fb * gb;
      }
    }
    ss[qa][tx] = s00 * scale; ss[qa][tx + 16] = s01 * scale;
    ss[qb][tx] = s10 * scale; ss[qb][tx + 16] = s11 * scale;
    __syncthreads();

    if (tid < 32){
      int r = tid;
      float mo = mrow[r], mx = mo;
      #pragma unroll
      for (int j = 0; j < 32; j++) mx = fmaxf(mx, ss[r][j]);
      float al = __expf(mo - mx);
      float sum = 0.f;
      #pragma unroll
      for (int j = 0; j < 32; j++){
        float p = __expf(ss[r][j] - mx);
        ss[r][j] = p; sum += p;
      }
      lrow[r] = lrow[r] * al + sum;
      mrow[r] = mx;
      arow[r] = al;
    }
    __syncthreads();

    float a0 = arow[qa], a1 = arow[qb];
    #pragma unroll
    for (int jj = 0; jj < 5; jj++){
      o0[jj][0] *= a0; o0[jj][1] *= a0;
      o1[jj][0] *= a1; o1[jj][1] *= a1;
    }
    #pragma unroll 4
    for (int kc = 0; kc < 32; kc++){
      float p0 = ss[qa][kc], p1 = ss[qb][kc];
      #pragma unroll
      for (int jj = 0; jj < 5; jj++){
        float2 v = *(const float2*)&vs[kc][2 * tx + 32 * jj];
        o0[jj][0] += p0 * v.x; o0[jj][1] += p0 * v.y;
        o1[jj][0] += p1 * v.x; o1[jj][1] += p1 * v.y;
      }
    }
  }

  float il0 = 1.0f / lrow[qa], il1 = 1.0f / lrow[qb];
  #pragma unroll
  for (int jj = 0; jj < 5; jj++){
    int col = h * 160 + 2 * tx + 32 * jj;
    out[(rowBase + qa) * 1280 + col]     = f2b(o0[jj][0] * il0);
    out[(rowBase + qa) * 1280 + col + 1] = f2b(o0[jj][1] * il0);
    out[(rowBase + qb) * 1280 + col]     = f2b(o1[jj][0] * il1);
    out[(rowBase + qb) * 1280 + col + 1] = f2b(o1[jj][1] * il1);
  }
}

// ---------- launcher ----------
extern "C" void kernel_launch(void* const* d_in, const int* in_sizes, int n_in,
                              void* d_out, int out_size, void* d_ws, size_t ws_size,
                              hipStream_t stream)
{
  const void* hid  = d_in[0];
  const void* pose = d_in[1];
  const void* wm   = d_in[2];
  const void* mb   = d_in[3];
  const void* wq   = d_in[4];
  const void* wk   = d_in[5];
  const void* wv   = d_in[6];
  const void* wo   = d_in[7];
  const void* bo   = d_in[8];
  const void* qd   = d_in[9];
  const void* qu   = d_in[10];
  const void* kd   = d_in[11];
  const void* ku   = d_in[12];
  const void* vd   = d_in[13];
  const void* vu   = d_in[14];
  const void* od   = d_in[15];
  const void* ou   = d_in[16];
  (void)in_sizes; (void)n_in; (void)out_size; (void)ws_size;

  // ws layout (u16 elems), total 46,858,240 u16 + 4B flag = 89.4 MiB
  u16* ws      = (u16*)d_ws;
  u16* qkv     = ws;                   // 31,457,280  [8192][3840]
  u16* t       = ws;                   // alias: dead before gemm2 writes qkv
  u16* x       = qkv + 31457280;       // 10,485,760  [8192][1280]
  u16* Wbuf    = x + 10485760;         //  4,915,200  [3840][1280] (reused)
  u16* attnout = x;                    // alias: x dead after gemm2
  int* flag    = (int*)(Wbuf + 4915200);

  detect_dtype<<<1, 64, 0, stream>>>((const u16*)hid, flag);
  // t = bf16(hid + pose)
  make_t<<<40960, 256, 0, stream>>>(hid, pose, t, flag);
  // x = t @ Wm^T' + mb + hid
  prep_w<<<6400, 256, 0, stream>>>(wm, nullptr, nullptr, Wbuf, 0, flag);
  gemm_bt<true, true, false><<<dim3(10, 64), 256, 0, stream>>>(
      t, Wbuf, mb, hid, x, 8192, 1280, 1280, flag);
  // qkv = x @ [Wq|Wk|Wv]_eff
  prep_w<<<6400, 256, 0, stream>>>(wq, qd, qu, Wbuf, 0, flag);
  prep_w<<<6400, 256, 0, stream>>>(wk, kd, ku, Wbuf, 1280, flag);
  prep_w<<<6400, 256, 0, stream>>>(wv, vd, vu, Wbuf, 2560, flag);
  gemm_bt<false, false, false><<<dim3(30, 64), 256, 0, stream>>>(
      x, Wbuf, nullptr, nullptr, qkv, 8192, 3840, 1280, flag);
  // attention
  attn_flash<<<dim3(32, 64), 256, 0, stream>>>(qkv, attnout);
  // out = attn @ Wo_eff + bo
  prep_w<<<6400, 256, 0, stream>>>(wo, od, ou, Wbuf, 0, flag);
  gemm_bt<true, false, true><<<dim3(10, 64), 256, 0, stream>>>(
      attnout, Wbuf, bo, nullptr, d_out, 8192, 1280, 1280, flag);
}

// Round 4
// 662.475 us; speedup vs baseline: 2.1599x; 2.1599x over previous
//
#include <hip/hip_runtime.h>
#include <stdint.h>

typedef unsigned short u16;
typedef __attribute__((ext_vector_type(8))) short short8;
typedef __attribute__((ext_vector_type(4))) float f32x4;

// ---------- bf16 helpers ----------
__device__ __forceinline__ float b2f(u16 x){
  union { unsigned u; float f; } v; v.u = ((unsigned)x) << 16; return v.f;
}
__device__ __forceinline__ float b2fs(short x){ return b2f((u16)x); }
__device__ __forceinline__ u16 f2b(float f){
  union { float f; unsigned u; } v; v.f = f;
  unsigned u = v.u;
  u += 0x7FFFu + ((u >> 16) & 1u);   // round-to-nearest-even
  return (u16)(u >> 16);
}
// dtype-flexible scalar load from a RAW harness input buffer
__device__ __forceinline__ float ldg_f(const void* p, int i, int f32){
  return f32 ? ((const float*)p)[i] : b2f(((const u16*)p)[i]);
}
// async global->LDS 16B (LDS dest must be wave-uniform base + lane*16)
__device__ __forceinline__ void gld16(const void* g, void* l){
  __builtin_amdgcn_global_load_lds(
      (__attribute__((address_space(1))) void*)(g),
      (__attribute__((address_space(3))) void*)(l), 16, 0, 0);
}

// ---------- kernel 0: detect raw input dtype (bf16 vs fp32) ----------
__global__ void detect_dtype(const u16* __restrict__ hid, int* __restrict__ flag){
  if (blockIdx.x == 0 && threadIdx.x == 0){
    int plaus = 0;
    for (int i = 0; i < 512; i++){
      u16 v = hid[2 * i];
      int e = (v >> 7) & 0xFF;
      if ((e >= 100 && e <= 140) || (v & 0x7FFF) == 0) plaus++;
    }
    *flag = (plaus < 400) ? 1 : 0;
  }
}

// ---------- kernel 1: t = bf16(hidden + pose) ----------
__global__ void make_t(const void* __restrict__ hid, const void* __restrict__ pose,
                       u16* __restrict__ t, const int* __restrict__ flag){
  int i = blockIdx.x * 256 + threadIdx.x;
  int f = *flag;
  t[i] = f2b(ldg_f(hid, i, f) + ldg_f(pose, i, f));
}

// ---------- kernel 2: WT[rowOff+n][k] = sc*(w[k][n] + rank-4 LoRA) ----------
__global__ void prep_w(const void* __restrict__ w, const void* __restrict__ dn,
                       const void* __restrict__ up, u16* __restrict__ WT,
                       int rowOff, float sc, const int* __restrict__ flag)
{
  int idx = blockIdx.x * 256 + threadIdx.x;   // 1280*1280 threads
  int k = idx % 1280, n = idx / 1280;
  int f = *flag;
  float val = ldg_f(w, k * 1280 + n, f);
  if (dn){
    #pragma unroll
    for (int r = 0; r < 4; r++)
      val += ldg_f(dn, k * 4 + r, f) * ldg_f(up, r * 1280 + n, f);
  }
  WT[(rowOff + n) * 1280 + k] = f2b(val * sc);
}

// ---------- kernel 3: bf16 MFMA GEMM: C = A @ BT^T (+bias)(+resid) ----------
// A [M][K] bf16 ws, BT [N][K] bf16 ws. bias/resid RAW (dtype flag).
// VSPLIT: cols <2560 row-major into Cout (width NOUT), cols>=2560 stored
// transposed into vtg[(b*8+h)*160+d][1024] (attention V layout).
template<bool BIAS, bool RESID, bool RAWOUT, bool VSPLIT>
__global__ __launch_bounds__(256) void gemm_bt(
    const u16* __restrict__ A, const u16* __restrict__ BT,
    const void* __restrict__ bias, const void* __restrict__ resid,
    void* __restrict__ Cout, u16* __restrict__ vtg,
    int Mdim, int NOUT, int Kdim, const int* __restrict__ flag)
{
  __shared__ alignas(16) u16 As[128 * 32];
  __shared__ alignas(16) u16 Bs[128 * 32];
  const int tid  = threadIdx.x;
  const int lane = tid & 63;
  const int w    = tid >> 6;
  const int wm   = w >> 1, wn = w & 1;
  const int quad = lane >> 4, l15 = lane & 15;
  const int tileM = blockIdx.y << 7;
  const int tileN = blockIdx.x << 7;
  const int f32 = (BIAS || RESID || RAWOUT) ? *flag : 0;

  f32x4 acc[4][4];
  #pragma unroll
  for (int mi = 0; mi < 4; mi++)
    #pragma unroll
    for (int ni = 0; ni < 4; ni++)
      acc[mi][ni] = (f32x4){0.f, 0.f, 0.f, 0.f};

  for (int k0 = 0; k0 < Kdim; k0 += 32){
    // stage via async global->LDS (m97): chunk c -> LDS linear c*16
    {
      int c = tid;
      gld16(&A [(tileM + (c >> 2)) * Kdim + k0 + ((c & 3) << 3)], (char*)As + c * 16);
      gld16(&BT[(tileN + (c >> 2)) * Kdim + k0 + ((c & 3) << 3)], (char*)Bs + c * 16);
      c = tid + 256;
      gld16(&A [(tileM + (c >> 2)) * Kdim + k0 + ((c & 3) << 3)], (char*)As + c * 16);
      gld16(&BT[(tileN + (c >> 2)) * Kdim + k0 + ((c & 3) << 3)], (char*)Bs + c * 16);
    }
    __syncthreads();               // drains vmcnt before barrier

    short8 af[4], bfr[4];
    #pragma unroll
    for (int mi = 0; mi < 4; mi++)
      af[mi] = *(const short8*)(As + (wm * 64 + mi * 16 + l15) * 32 + quad * 8);
    #pragma unroll
    for (int ni = 0; ni < 4; ni++)
      bfr[ni] = *(const short8*)(Bs + (wn * 64 + ni * 16 + l15) * 32 + quad * 8);
    #pragma unroll
    for (int mi = 0; mi < 4; mi++)
      #pragma unroll
      for (int ni = 0; ni < 4; ni++)
        acc[mi][ni] = __builtin_amdgcn_mfma_f32_16x16x32_bf16(
            af[mi], bfr[ni], acc[mi][ni], 0, 0, 0);
    __syncthreads();
  }

  // epilogue: C/D layout col=lane&15, row=quad*4+reg  [m89/m91 verified]
  if (VSPLIT && tileN >= 2560){
    // transposed V store: 4 regs = 4 consecutive s-rows = contiguous 8B
    #pragma unroll
    for (int mi = 0; mi < 4; mi++){
      #pragma unroll
      for (int ni = 0; ni < 4; ni++){
        int col = tileN + wn * 64 + ni * 16 + l15;
        int hd = col - 2560;
        int hh = hd / 160;
        int dd = hd - hh * 160;
        int row0 = tileM + wm * 64 + mi * 16 + quad * 4;
        int bb = row0 >> 10;
        long addr = ((long)((bb * 8 + hh) * 160 + dd) << 10) | (long)(row0 & 1023);
        ushort4 pk;
        pk.x = f2b(acc[mi][ni][0]); pk.y = f2b(acc[mi][ni][1]);
        pk.z = f2b(acc[mi][ni][2]); pk.w = f2b(acc[mi][ni][3]);
        *(ushort4*)&vtg[addr] = pk;
      }
    }
  } else {
    #pragma unroll
    for (int mi = 0; mi < 4; mi++){
      #pragma unroll
      for (int ni = 0; ni < 4; ni++){
        int col = tileN + wn * 64 + ni * 16 + l15;
        float bv = 0.f;
        if (BIAS) bv = ldg_f(bias, col, f32);
        #pragma unroll
        for (int r = 0; r < 4; r++){
          int row = tileM + wm * 64 + mi * 16 + quad * 4 + r;
          float v = acc[mi][ni][r] + bv;
          if (RESID) v += ldg_f(resid, row * NOUT, f32 * 0 + f32) * 0.f + // keep layout simple below
                          0.f;
          (void)0;
          if (RESID) v += ldg_f(resid, row * NOUT + col, f32) - ldg_f(resid, row * NOUT, f32) * 0.f;
          if (RAWOUT && f32) ((float*)Cout)[row * NOUT + col] = v;
          else               ((u16*)Cout)[row * NOUT + col]   = f2b(v);
        }
      }
    }
  }
}

// ---------- kernel 4: MFMA flash attention ----------
// qk [8192][2560] bf16 (q|k per head h at col h*160 / 1280+h*160)
// vtg [64 bh][160 d][1024 s] bf16. out [8192][1280] bf16.
// Block: 128 q-rows of one (b,h); 4 waves x 32 rows; TK=64; 16 K-iters.
__global__ __launch_bounds__(256, 2) void attn_mfma(
    const u16* __restrict__ qk, const u16* __restrict__ vtg,
    u16* __restrict__ out)
{
  __shared__ alignas(16) u16 Ks[64 * 160];   // stride 160 (bank ~ m97 pattern)
  __shared__ alignas(16) u16 Vt[160 * 72];   // [d][k], pad->72 (2-way max)
  __shared__ alignas(16) u16 Ps[4 * 32 * 72];// per-wave P, pad->72

  const int tid  = threadIdx.x, lane = tid & 63, wv = tid >> 6;
  const int quad = lane >> 4,   l15  = lane & 15;
  // XCD swizzle: all 8 q-tiles of one (b,h) share blockIdx.x -> same XCD L2
  const int bh = ((blockIdx.y >> 3) << 3) | blockIdx.x;
  const int qt = blockIdx.y & 7;
  const int b  = bh >> 3, h = bh & 7;
  const int rowBase = (b << 10) + (qt << 7);
  const int kBase   = b << 10;

  // Q fragments in registers (scale pre-folded into Wq): 2 m-frags x 5 k-steps
  short8 qa[2][5];
  #pragma unroll
  for (int mi = 0; mi < 2; mi++)
    #pragma unroll
    for (int kk = 0; kk < 5; kk++)
      qa[mi][kk] = *(const short8*)&qk[
          (rowBase + wv * 32 + mi * 16 + l15) * 2560 + h * 160 + kk * 32 + quad * 8];

  f32x4 o[2][10];
  #pragma unroll
  for (int mi = 0; mi < 2; mi++)
    #pragma unroll
    for (int ni = 0; ni < 10; ni++)
      o[mi][ni] = (f32x4){0.f, 0.f, 0.f, 0.f};
  float mr[2][4], lr[2][4];
  #pragma unroll
  for (int mi = 0; mi < 2; mi++)
    #pragma unroll
    for (int r = 0; r < 4; r++){ mr[mi][r] = -1e30f; lr[mi][r] = 0.f; }

  for (int kt = 0; kt < 16; kt++){
    __syncthreads();                       // prev-iter LDS reads done
    // stage K-tile [64][160] via async global->LDS (LDS linear in chunk)
    #pragma unroll
    for (int i = 0; i < 5; i++){
      int c  = tid + (i << 8);
      int kr = c / 20, kc = c % 20;
      gld16(&qk[(kBase + (kt << 6) + kr) * 2560 + 1280 + h * 160 + (kc << 3)],
            (char*)Ks + c * 16);
    }
    // stage Vt-tile [160][64->72] explicit (pad breaks gld16 linearity)
    #pragma unroll
    for (int i = 0; i < 5; i++){
      int c = tid + (i << 8);
      int d = c >> 3, kc = c & 7;
      short8 v = *(const short8*)&vtg[((bh * 160 + d) << 10) + (kt << 6) + (kc << 3)];
      *(short8*)&Vt[d * 72 + (kc << 3)] = v;
    }
    __syncthreads();                       // drains vmcnt + lgkm

    // S = Q @ K^T  (S[q][kcol]; C-layout: col=l15->k-row, row=quad*4+r->q)
    f32x4 s[2][4];
    #pragma unroll
    for (int mi = 0; mi < 2; mi++)
      #pragma unroll
      for (int ni = 0; ni < 4; ni++)
        s[mi][ni] = (f32x4){0.f, 0.f, 0.f, 0.f};
    #pragma unroll
    for (int kk = 0; kk < 5; kk++){
      #pragma unroll
      for (int ni = 0; ni < 4; ni++){
        short8 bf = *(const short8*)&Ks[(ni * 16 + l15) * 160 + kk * 32 + quad * 8];
        s[0][ni] = __builtin_amdgcn_mfma_f32_16x16x32_bf16(qa[0][kk], bf, s[0][ni], 0, 0, 0);
        s[1][ni] = __builtin_amdgcn_mfma_f32_16x16x32_bf16(qa[1][kk], bf, s[1][ni], 0, 0, 0);
      }
    }

    // online softmax: rows per lane = mi*16 + quad*4 + r; cols across l15
    float al[2][4];
    #pragma unroll
    for (int mi = 0; mi < 2; mi++){
      #pragma unroll
      for (int r = 0; r < 4; r++){
        float mx = fmaxf(fmaxf(s[mi][0][r], s[mi][1][r]),
                         fmaxf(s[mi][2][r], s[mi][3][r]));
        #pragma unroll
        for (int xm = 1; xm < 16; xm <<= 1) mx = fmaxf(mx, __shfl_xor(mx, xm, 64));
        float mn = fmaxf(mr[mi][r], mx);
        float a  = __expf(mr[mi][r] - mn);
        mr[mi][r] = mn; al[mi][r] = a;
        float sum = 0.f;
        #pragma unroll
        for (int ni = 0; ni < 4; ni++){
          float p = __expf(s[mi][ni][r] - mn);
          s[mi][ni][r] = p; sum += p;
        }
        #pragma unroll
        for (int xm = 1; xm < 16; xm <<= 1) sum += __shfl_xor(sum, xm, 64);
        lr[mi][r] = lr[mi][r] * a + sum;
      }
    }
    // P -> LDS (C-layout scatter; ~2-way banks), rescale O by alpha
    #pragma unroll
    for (int mi = 0; mi < 2; mi++)
      #pragma unroll
      for (int ni = 0; ni < 4; ni++)
        #pragma unroll
        for (int r = 0; r < 4; r++)
          Ps[wv * 2304 + (mi * 16 + quad * 4 + r) * 72 + ni * 16 + l15] =
              f2b(s[mi][ni][r]);
    #pragma unroll
    for (int mi = 0; mi < 2; mi++)
      #pragma unroll
      for (int ni = 0; ni < 10; ni++)
        #pragma unroll
        for (int r = 0; r < 4; r++)
          o[mi][ni][r] *= al[mi][r];

    // O += P @ V   (A-frags from Ps rows=q; B-frags from Vt rows=d)
    #pragma unroll
    for (int kk2 = 0; kk2 < 2; kk2++){
      short8 pa0 = *(const short8*)&Ps[wv * 2304 + l15 * 72        + kk2 * 32 + quad * 8];
      short8 pa1 = *(const short8*)&Ps[wv * 2304 + (16 + l15) * 72 + kk2 * 32 + quad * 8];
      #pragma unroll
      for (int ni = 0; ni < 10; ni++){
        short8 vf = *(const short8*)&Vt[(ni * 16 + l15) * 72 + kk2 * 32 + quad * 8];
        o[0][ni] = __builtin_amdgcn_mfma_f32_16x16x32_bf16(pa0, vf, o[0][ni], 0, 0, 0);
        o[1][ni] = __builtin_amdgcn_mfma_f32_16x16x32_bf16(pa1, vf, o[1][ni], 0, 0, 0);
      }
    }
  }

  // epilogue: O /= l
  #pragma unroll
  for (int mi = 0; mi < 2; mi++){
    #pragma unroll
    for (int r = 0; r < 4; r++){
      float inv = 1.0f / lr[mi][r];
      int row = rowBase + wv * 32 + mi * 16 + quad * 4 + r;
      #pragma unroll
      for (int ni = 0; ni < 10; ni++)
        out[row * 1280 + h * 160 + ni * 16 + l15] = f2b(o[mi][ni][r] * inv);
    }
  }
}

// ---------- launcher ----------
extern "C" void kernel_launch(void* const* d_in, const int* in_sizes, int n_in,
                              void* d_out, int out_size, void* d_ws, size_t ws_size,
                              hipStream_t stream)
{
  const void* hid  = d_in[0];
  const void* pose = d_in[1];
  const void* wm   = d_in[2];
  const void* mb   = d_in[3];
  const void* wq   = d_in[4];
  const void* wk   = d_in[5];
  const void* wv   = d_in[6];
  const void* wo   = d_in[7];
  const void* bo   = d_in[8];
  const void* qd   = d_in[9];
  const void* qu   = d_in[10];
  const void* kd   = d_in[11];
  const void* ku   = d_in[12];
  const void* vd   = d_in[13];
  const void* vu   = d_in[14];
  const void* od   = d_in[15];
  const void* ou   = d_in[16];
  (void)in_sizes; (void)n_in; (void)out_size; (void)ws_size;

  // ws layout (u16 elems), total 46,858,240 u16 + 4B flag = 89.4 MiB (same as R3)
  u16* ws   = (u16*)d_ws;
  u16* qk   = ws;                    // 20,971,520  [8192][2560]
  u16* t    = qk;                    // alias: dead before gemm2 writes qk
  u16* x    = qk + 20971520;         // 10,485,760  [8192][1280]
  u16* vtg  = x + 10485760;          // 10,485,760  [64][160][1024]
  u16* Wbuf = vtg + 10485760;        //  4,915,200  [3840][1280] (reused)
  u16* attnout = x;                  // alias: x dead after gemm2
  int* flag = (int*)(Wbuf + 4915200);

  const float qscale = 0.07905694150420949f;  // 160^-0.5 folded into Wq

  detect_dtype<<<1, 64, 0, stream>>>((const u16*)hid, flag);
  make_t<<<40960, 256, 0, stream>>>(hid, pose, t, flag);
  // x = t @ Wm^T' + mb + hid
  prep_w<<<6400, 256, 0, stream>>>(wm, nullptr, nullptr, Wbuf, 0, 1.0f, flag);
  gemm_bt<true, true, false, false><<<dim3(10, 64), 256, 0, stream>>>(
      t, Wbuf, mb, hid, x, nullptr, 8192, 1280, 1280, flag);
  // qk | vtg = x @ [Wq*s|Wk|Wv]_eff
  prep_w<<<6400, 256, 0, stream>>>(wq, qd, qu, Wbuf, 0, qscale, flag);
  prep_w<<<6400, 256, 0, stream>>>(wk, kd, ku, Wbuf, 1280, 1.0f, flag);
  prep_w<<<6400, 256, 0, stream>>>(wv, vd, vu, Wbuf, 2560, 1.0f, flag);
  gemm_bt<false, false, false, true><<<dim3(30, 64), 256, 0, stream>>>(
      x, Wbuf, nullptr, nullptr, qk, vtg, 8192, 2560, 1280, flag);
  // attention
  attn_mfma<<<dim3(8, 64), 256, 0, stream>>>(qk, vtg, attnout);
  // out = attn @ Wo_eff + bo
  prep_w<<<6400, 256, 0, stream>>>(wo, od, ou, Wbuf, 0, 1.0f, flag);
  gemm_bt<true, false, true, false><<<dim3(10, 64), 256, 0, stream>>>(
      attnout, Wbuf, bo, nullptr, d_out, nullptr, 8192, 1280, 1280, flag);
}

// Round 5
// 633.696 us; speedup vs baseline: 2.2580x; 1.0454x over previous
//
#include <hip/hip_runtime.h>
#include <stdint.h>

typedef unsigned short u16;
typedef __attribute__((ext_vector_type(8))) short short8;
typedef __attribute__((ext_vector_type(4))) float f32x4;

// ---------- bf16 helpers ----------
__device__ __forceinline__ float b2f(u16 x){
  union { unsigned u; float f; } v; v.u = ((unsigned)x) << 16; return v.f;
}
__device__ __forceinline__ float b2fs(short x){ return b2f((u16)x); }
__device__ __forceinline__ u16 f2b(float f){
  union { float f; unsigned u; } v; v.f = f;
  unsigned u = v.u;
  u += 0x7FFFu + ((u >> 16) & 1u);   // round-to-nearest-even
  return (u16)(u >> 16);
}
// dtype-flexible scalar load from a RAW harness input buffer
__device__ __forceinline__ float ldg_f(const void* p, int i, int f32){
  return f32 ? ((const float*)p)[i] : b2f(((const u16*)p)[i]);
}
// async global->LDS 16B (LDS dest must be wave-uniform base + lane*16)
__device__ __forceinline__ void gld16(const void* g, void* l){
  __builtin_amdgcn_global_load_lds(
      (__attribute__((address_space(1))) void*)(g),
      (__attribute__((address_space(3))) void*)(l), 16, 0, 0);
}

// ---------- kernel 0: detect raw input dtype (bf16 vs fp32) ----------
__global__ void detect_dtype(const u16* __restrict__ hid, int* __restrict__ flag){
  if (blockIdx.x == 0 && threadIdx.x == 0){
    int plaus = 0;
    for (int i = 0; i < 512; i++){
      u16 v = hid[2 * i];
      int e = (v >> 7) & 0xFF;
      if ((e >= 100 && e <= 140) || (v & 0x7FFF) == 0) plaus++;
    }
    *flag = (plaus < 400) ? 1 : 0;
  }
}

// ---------- kernel 1: t = bf16(hidden + pose), 8 elems/thread ----------
__global__ void make_t(const void* __restrict__ hid, const void* __restrict__ pose,
                       u16* __restrict__ t, const int* __restrict__ flag){
  int base = (blockIdx.x * 256 + threadIdx.x) * 8;
  short8 o;
  if (*flag){
    #pragma unroll
    for (int j = 0; j < 2; j++){
      float4 a = *(const float4*)((const float*)hid  + base + j * 4);
      float4 b = *(const float4*)((const float*)pose + base + j * 4);
      o[j * 4 + 0] = (short)f2b(a.x + b.x);
      o[j * 4 + 1] = (short)f2b(a.y + b.y);
      o[j * 4 + 2] = (short)f2b(a.z + b.z);
      o[j * 4 + 3] = (short)f2b(a.w + b.w);
    }
  } else {
    short8 a = *(const short8*)((const u16*)hid  + base);
    short8 b = *(const short8*)((const u16*)pose + base);
    #pragma unroll
    for (int j = 0; j < 8; j++) o[j] = (short)f2b(b2fs(a[j]) + b2fs(b[j]));
  }
  *(short8*)(t + base) = o;
}

// ---------- kernel 2: coalesced transpose + rank-4 LoRA fold ----------
// WT[rowOff+n][k] = sc*(w[k][n] + dn[k][:]·up[:][n]).  64x64 tiles via LDS.
__global__ void prep_w(const void* __restrict__ w, const void* __restrict__ dn,
                       const void* __restrict__ up, u16* __restrict__ WT,
                       int rowOff, float sc, const int* __restrict__ flag)
{
  __shared__ float tile[64][65];            // 65 ≡ 1 mod 32 -> ≤2-way banks
  const int f = *flag;
  const int k0 = blockIdx.x * 64, n0 = blockIdx.y * 64;
  const int tr  = threadIdx.x >> 2;         // 0..63
  const int tc0 = (threadIdx.x & 3) * 16;   // 0,16,32,48
  // load w[k0+tr][n0+tc0 .. +16] (coalesced)
  #pragma unroll
  for (int i = 0; i < 16; i++)
    tile[tr][tc0 + i] = ldg_f(w, (k0 + tr) * 1280 + n0 + tc0 + i, f);
  __syncthreads();
  // write transposed: n = n0+tr, k = k0+tc0 .. +16 (coalesced 32B stores)
  const int n = n0 + tr;
  float upv[4];
  if (dn){
    #pragma unroll
    for (int r = 0; r < 4; r++) upv[r] = ldg_f(up, r * 1280 + n, f);
  }
  u16 tmp[16];
  #pragma unroll
  for (int i = 0; i < 16; i++){
    int k = k0 + tc0 + i;
    float val = tile[tc0 + i][tr];
    if (dn){
      #pragma unroll
      for (int r = 0; r < 4; r++)
        val += ldg_f(dn, k * 4 + r, f) * upv[r];
    }
    tmp[i] = f2b(val * sc);
  }
  u16* dst = &WT[(rowOff + n) * 1280 + k0 + tc0];
  #pragma unroll
  for (int i = 0; i < 4; i++)
    *(ushort4*)(dst + i * 4) = *(ushort4*)(tmp + i * 4);
}

// ---------- kernel 3: bf16 MFMA GEMM: C = A @ BT^T (+bias)(+resid) ----------
// A [M][K] bf16 ws, BT [N][K] bf16 ws. bias/resid RAW (dtype flag).
// VSPLIT: cols <2560 row-major into Cout (width NOUT), cols>=2560 stored
// transposed into vtg[(b*8+h)*160+d][1024] (attention V layout).
template<bool BIAS, bool RESID, bool RAWOUT, bool VSPLIT>
__global__ __launch_bounds__(256) void gemm_bt(
    const u16* __restrict__ A, const u16* __restrict__ BT,
    const void* __restrict__ bias, const void* __restrict__ resid,
    void* __restrict__ Cout, u16* __restrict__ vtg,
    int n0off, int NOUT, int Kdim, const int* __restrict__ flag)
{
  __shared__ alignas(16) u16 As[128 * 32];
  __shared__ alignas(16) u16 Bs[128 * 32];
  const int tid  = threadIdx.x;
  const int lane = tid & 63;
  const int w    = tid >> 6;
  const int wm   = w >> 1, wn = w & 1;
  const int quad = lane >> 4, l15 = lane & 15;
  const int tileM = blockIdx.y << 7;
  const int tileN = (blockIdx.x + n0off) << 7;
  const int f32 = (BIAS || RESID || RAWOUT) ? *flag : 0;

  f32x4 acc[4][4];
  #pragma unroll
  for (int mi = 0; mi < 4; mi++)
    #pragma unroll
    for (int ni = 0; ni < 4; ni++)
      acc[mi][ni] = (f32x4){0.f, 0.f, 0.f, 0.f};

  for (int k0 = 0; k0 < Kdim; k0 += 32){
    // stage via async global->LDS (m97): chunk c -> LDS linear c*16
    {
      int c = tid;
      gld16(&A [(tileM + (c >> 2)) * Kdim + k0 + ((c & 3) << 3)], (char*)As + c * 16);
      gld16(&BT[(tileN + (c >> 2)) * Kdim + k0 + ((c & 3) << 3)], (char*)Bs + c * 16);
      c = tid + 256;
      gld16(&A [(tileM + (c >> 2)) * Kdim + k0 + ((c & 3) << 3)], (char*)As + c * 16);
      gld16(&BT[(tileN + (c >> 2)) * Kdim + k0 + ((c & 3) << 3)], (char*)Bs + c * 16);
    }
    __syncthreads();

    short8 af[4], bfr[4];
    #pragma unroll
    for (int mi = 0; mi < 4; mi++)
      af[mi] = *(const short8*)(As + (wm * 64 + mi * 16 + l15) * 32 + quad * 8);
    #pragma unroll
    for (int ni = 0; ni < 4; ni++)
      bfr[ni] = *(const short8*)(Bs + (wn * 64 + ni * 16 + l15) * 32 + quad * 8);
    #pragma unroll
    for (int mi = 0; mi < 4; mi++)
      #pragma unroll
      for (int ni = 0; ni < 4; ni++)
        acc[mi][ni] = __builtin_amdgcn_mfma_f32_16x16x32_bf16(
            af[mi], bfr[ni], acc[mi][ni], 0, 0, 0);
    __syncthreads();
  }

  // epilogue: C/D layout col=lane&15, row=quad*4+reg  [m89/m91 verified]
  if (VSPLIT && tileN >= 2560){
    // transposed V store: 4 regs = 4 consecutive s-rows = contiguous 8B
    #pragma unroll
    for (int mi = 0; mi < 4; mi++){
      #pragma unroll
      for (int ni = 0; ni < 4; ni++){
        int col = tileN + wn * 64 + ni * 16 + l15;
        int hd = col - 2560;
        int hh = hd / 160;
        int dd = hd - hh * 160;
        int row0 = tileM + wm * 64 + mi * 16 + quad * 4;
        int bb = row0 >> 10;
        long addr = ((long)((bb * 8 + hh) * 160 + dd) << 10) | (long)(row0 & 1023);
        ushort4 pk;
        pk.x = f2b(acc[mi][ni][0]); pk.y = f2b(acc[mi][ni][1]);
        pk.z = f2b(acc[mi][ni][2]); pk.w = f2b(acc[mi][ni][3]);
        *(ushort4*)&vtg[addr] = pk;
      }
    }
  } else {
    #pragma unroll
    for (int mi = 0; mi < 4; mi++){
      #pragma unroll
      for (int ni = 0; ni < 4; ni++){
        int col = tileN + wn * 64 + ni * 16 + l15;
        float bv = 0.f;
        if (BIAS) bv = ldg_f(bias, col, f32);
        #pragma unroll
        for (int r = 0; r < 4; r++){
          int row = tileM + wm * 64 + mi * 16 + quad * 4 + r;
          float v = acc[mi][ni][r] + bv;
          if (RESID) v += ldg_f(resid, row * NOUT + col, f32);
          if (RAWOUT && f32) ((float*)Cout)[row * NOUT + col] = v;
          else               ((u16*)Cout)[row * NOUT + col]   = f2b(v);
        }
      }
    }
  }
}

// ---------- kernel 4: MFMA flash attention ----------
// qk [8192][2560] bf16 (q|k per head h at col h*160 / 1280+h*160)
// vtg [64 bh][160 d][1024 s] bf16. out [8192][1280] bf16.
// Block: 128 q-rows of one (b,h); 4 waves x 32 rows; TK=64; 16 K-iters.
__global__ __launch_bounds__(256, 2) void attn_mfma(
    const u16* __restrict__ qk, const u16* __restrict__ vtg,
    u16* __restrict__ out)
{
  __shared__ alignas(16) u16 Ks[64 * 160];   // stride 160 (bank ~ m97 pattern)
  __shared__ alignas(16) u16 Vt[160 * 72];   // [d][k], pad->72 (2-way max)
  __shared__ alignas(16) u16 Ps[4 * 32 * 72];// per-wave P, pad->72

  const int tid  = threadIdx.x, lane = tid & 63, wv = tid >> 6;
  const int quad = lane >> 4,   l15  = lane & 15;
  // XCD swizzle: all 8 q-tiles of one (b,h) share blockIdx.x -> same XCD L2
  const int bh = ((blockIdx.y >> 3) << 3) | blockIdx.x;
  const int qt = blockIdx.y & 7;
  const int b  = bh >> 3, h = bh & 7;
  const int rowBase = (b << 10) + (qt << 7);
  const int kBase   = b << 10;

  // Q fragments in registers (scale pre-folded into Wq): 2 m-frags x 5 k-steps
  short8 qa[2][5];
  #pragma unroll
  for (int mi = 0; mi < 2; mi++)
    #pragma unroll
    for (int kk = 0; kk < 5; kk++)
      qa[mi][kk] = *(const short8*)&qk[
          (rowBase + wv * 32 + mi * 16 + l15) * 2560 + h * 160 + kk * 32 + quad * 8];

  f32x4 o[2][10];
  #pragma unroll
  for (int mi = 0; mi < 2; mi++)
    #pragma unroll
    for (int ni = 0; ni < 10; ni++)
      o[mi][ni] = (f32x4){0.f, 0.f, 0.f, 0.f};
  float mr[2][4], lr[2][4];
  #pragma unroll
  for (int mi = 0; mi < 2; mi++)
    #pragma unroll
    for (int r = 0; r < 4; r++){ mr[mi][r] = -1e30f; lr[mi][r] = 0.f; }

  for (int kt = 0; kt < 16; kt++){
    __syncthreads();                       // prev-iter LDS reads done
    // stage K-tile [64][160] via async global->LDS (LDS linear in chunk)
    #pragma unroll
    for (int i = 0; i < 5; i++){
      int c  = tid + (i << 8);
      int kr = c / 20, kc = c % 20;
      gld16(&qk[(kBase + (kt << 6) + kr) * 2560 + 1280 + h * 160 + (kc << 3)],
            (char*)Ks + c * 16);
    }
    // stage Vt-tile [160][64->72] explicit (pad breaks gld16 linearity)
    #pragma unroll
    for (int i = 0; i < 5; i++){
      int c = tid + (i << 8);
      int d = c >> 3, kc = c & 7;
      short8 v = *(const short8*)&vtg[((bh * 160 + d) << 10) + (kt << 6) + (kc << 3)];
      *(short8*)&Vt[d * 72 + (kc << 3)] = v;
    }
    __syncthreads();                       // drains vmcnt + lgkm

    // S = Q @ K^T  (S[q][kcol]; C-layout: col=l15->k-row, row=quad*4+r->q)
    f32x4 s[2][4];
    #pragma unroll
    for (int mi = 0; mi < 2; mi++)
      #pragma unroll
      for (int ni = 0; ni < 4; ni++)
        s[mi][ni] = (f32x4){0.f, 0.f, 0.f, 0.f};
    #pragma unroll
    for (int kk = 0; kk < 5; kk++){
      #pragma unroll
      for (int ni = 0; ni < 4; ni++){
        short8 bf = *(const short8*)&Ks[(ni * 16 + l15) * 160 + kk * 32 + quad * 8];
        s[0][ni] = __builtin_amdgcn_mfma_f32_16x16x32_bf16(qa[0][kk], bf, s[0][ni], 0, 0, 0);
        s[1][ni] = __builtin_amdgcn_mfma_f32_16x16x32_bf16(qa[1][kk], bf, s[1][ni], 0, 0, 0);
      }
    }

    // online softmax: rows per lane = mi*16 + quad*4 + r; cols across l15
    float al[2][4];
    #pragma unroll
    for (int mi = 0; mi < 2; mi++){
      #pragma unroll
      for (int r = 0; r < 4; r++){
        float mx = fmaxf(fmaxf(s[mi][0][r], s[mi][1][r]),
                         fmaxf(s[mi][2][r], s[mi][3][r]));
        #pragma unroll
        for (int xm = 1; xm < 16; xm <<= 1) mx = fmaxf(mx, __shfl_xor(mx, xm, 64));
        float mn = fmaxf(mr[mi][r], mx);
        float a  = __expf(mr[mi][r] - mn);
        mr[mi][r] = mn; al[mi][r] = a;
        float sum = 0.f;
        #pragma unroll
        for (int ni = 0; ni < 4; ni++){
          float p = __expf(s[mi][ni][r] - mn);
          s[mi][ni][r] = p; sum += p;
        }
        #pragma unroll
        for (int xm = 1; xm < 16; xm <<= 1) sum += __shfl_xor(sum, xm, 64);
        lr[mi][r] = lr[mi][r] * a + sum;
      }
    }
    // P -> LDS (C-layout scatter; ~2-way banks), rescale O by alpha
    #pragma unroll
    for (int mi = 0; mi < 2; mi++)
      #pragma unroll
      for (int ni = 0; ni < 4; ni++)
        #pragma unroll
        for (int r = 0; r < 4; r++)
          Ps[wv * 2304 + (mi * 16 + quad * 4 + r) * 72 + ni * 16 + l15] =
              f2b(s[mi][ni][r]);
    #pragma unroll
    for (int mi = 0; mi < 2; mi++)
      #pragma unroll
      for (int ni = 0; ni < 10; ni++)
        #pragma unroll
        for (int r = 0; r < 4; r++)
          o[mi][ni][r] *= al[mi][r];

    // O += P @ V   (A-frags from Ps rows=q; B-frags from Vt rows=d)
    #pragma unroll
    for (int kk2 = 0; kk2 < 2; kk2++){
      short8 pa0 = *(const short8*)&Ps[wv * 2304 + l15 * 72        + kk2 * 32 + quad * 8];
      short8 pa1 = *(const short8*)&Ps[wv * 2304 + (16 + l15) * 72 + kk2 * 32 + quad * 8];
      #pragma unroll
      for (int ni = 0; ni < 10; ni++){
        short8 vf = *(const short8*)&Vt[(ni * 16 + l15) * 72 + kk2 * 32 + quad * 8];
        o[0][ni] = __builtin_amdgcn_mfma_f32_16x16x32_bf16(pa0, vf, o[0][ni], 0, 0, 0);
        o[1][ni] = __builtin_amdgcn_mfma_f32_16x16x32_bf16(pa1, vf, o[1][ni], 0, 0, 0);
      }
    }
  }

  // epilogue: O /= l
  #pragma unroll
  for (int mi = 0; mi < 2; mi++){
    #pragma unroll
    for (int r = 0; r < 4; r++){
      float inv = 1.0f / lr[mi][r];
      int row = rowBase + wv * 32 + mi * 16 + quad * 4 + r;
      #pragma unroll
      for (int ni = 0; ni < 10; ni++)
        out[row * 1280 + h * 160 + ni * 16 + l15] = f2b(o[mi][ni][r] * inv);
    }
  }
}

// ---------- launcher ----------
extern "C" void kernel_launch(void* const* d_in, const int* in_sizes, int n_in,
                              void* d_out, int out_size, void* d_ws, size_t ws_size,
                              hipStream_t stream)
{
  const void* hid  = d_in[0];
  const void* pose = d_in[1];
  const void* wm   = d_in[2];
  const void* mb   = d_in[3];
  const void* wq   = d_in[4];
  const void* wk   = d_in[5];
  const void* wv   = d_in[6];
  const void* wo   = d_in[7];
  const void* bo   = d_in[8];
  const void* qd   = d_in[9];
  const void* qu   = d_in[10];
  const void* kd   = d_in[11];
  const void* ku   = d_in[12];
  const void* vd   = d_in[13];
  const void* vu   = d_in[14];
  const void* od   = d_in[15];
  const void* ou   = d_in[16];
  (void)in_sizes; (void)n_in; (void)out_size; (void)ws_size;

  // ws layout (u16 elems), total 46,858,240 u16 + 4B flag = 89.4 MiB
  u16* ws   = (u16*)d_ws;
  u16* qk   = ws;                    // 20,971,520  [8192][2560]
  u16* t    = qk;                    // alias: dead before gemm2 writes qk
  u16* x    = qk + 20971520;         // 10,485,760  [8192][1280]
  u16* vtg  = x + 10485760;          // 10,485,760  [64][160][1024]
  u16* Wbuf = vtg + 10485760;        //  4,915,200  [3840][1280] (reused)
  u16* attnout = x;                  // alias: x dead after gemm2
  int* flag = (int*)(Wbuf + 4915200);

  const float qscale = 0.07905694150420949f;  // 160^-0.5 folded into Wq

  detect_dtype<<<1, 64, 0, stream>>>((const u16*)hid, flag);
  make_t<<<5120, 256, 0, stream>>>(hid, pose, t, flag);
  // x = t @ Wm^T' + mb + hid
  prep_w<<<dim3(20, 20), 256, 0, stream>>>(wm, nullptr, nullptr, Wbuf, 0, 1.0f, flag);
  gemm_bt<true, true, false, false><<<dim3(10, 64), 256, 0, stream>>>(
      t, Wbuf, mb, hid, x, nullptr, 0, 1280, 1280, flag);
  // qk | vtg = x @ [Wq*s|Wk|Wv]_eff  (split into 2 launches: diagnostic)
  prep_w<<<dim3(20, 20), 256, 0, stream>>>(wq, qd, qu, Wbuf, 0, qscale, flag);
  prep_w<<<dim3(20, 20), 256, 0, stream>>>(wk, kd, ku, Wbuf, 1280, 1.0f, flag);
  prep_w<<<dim3(20, 20), 256, 0, stream>>>(wv, vd, vu, Wbuf, 2560, 1.0f, flag);
  gemm_bt<false, false, false, true><<<dim3(15, 64), 256, 0, stream>>>(
      x, Wbuf, nullptr, nullptr, qk, vtg, 0, 2560, 1280, flag);
  gemm_bt<false, false, false, true><<<dim3(15, 64), 256, 0, stream>>>(
      x, Wbuf, nullptr, nullptr, qk, vtg, 15, 2560, 1280, flag);
  // attention
  attn_mfma<<<dim3(8, 64), 256, 0, stream>>>(qk, vtg, attnout);
  // out = attn @ Wo_eff + bo
  prep_w<<<dim3(20, 20), 256, 0, stream>>>(wo, od, ou, Wbuf, 0, 1.0f, flag);
  gemm_bt<true, false, true, false><<<dim3(10, 64), 256, 0, stream>>>(
      attnout, Wbuf, bo, nullptr, d_out, nullptr, 0, 1280, 1280, flag);
}